// Round 2
// baseline (1467.994 us; speedup 1.0000x reference)
//
#include <hip/hip_runtime.h>

typedef unsigned int u32;
typedef unsigned short u16;

#define B_   512
#define L_   201
#define T_   200
#define H_   128
#define V_   100001
#define G3_  384
#define M_   (B_*T_)   // 102400

// ws layout (bytes):
//   [0,16)            : dtype flag (int) written by k_sniff: 1=fp32 inputs, 0=bf16 inputs
//   [256, +25600256)  : embT  (V,H) bf16
//   [25600768, +26214400) : x (M,H) bf16   (offset padded to 256)
//   [51815168, ...)   : gi (M,384) fp32 (157286400 B) if ws fits, else bf16 (78643200 B)
#define OFF_EMBT  256
#define OFF_X     25600768ull
#define OFF_GI    51815168ull

__device__ __forceinline__ float bf2f(u16 a) {
    return __uint_as_float(((u32)a) << 16);
}
__device__ __forceinline__ void bf2x2(u32 p, float& lo, float& hi) {
    lo = __uint_as_float(p << 16);
    hi = __uint_as_float(p & 0xffff0000u);
}
__device__ __forceinline__ u16 f2bf(float f) {
    u32 u = __float_as_uint(f);
    u32 lsb = (u >> 16) & 1u;
    u += 0x7fffu + lsb;   // RNE
    return (u16)(u >> 16);
}
__device__ __forceinline__ u32 packbf(float a, float b) {
    return (u32)f2bf(a) | ((u32)f2bf(b) << 16);
}
__device__ __forceinline__ float sigmoidf_(float x) {
    return 1.0f / (1.0f + __expf(-x));
}
__device__ __forceinline__ float tanhf_(float x) {
    float e = __expf(2.0f * x);
    return 1.0f - 2.0f / (e + 1.0f);
}

// ---------------- K0: dtype sniffer --------------------------------------------
// fp32 data: low 16 bits of each u32 are random mantissa bits -> as bf16 often
// |v|>16 or NaN. bf16 data (~N(0,0.02)): never. One wave, 1024 u32 scan.
__global__ __launch_bounds__(64) void k_sniff(const u32* __restrict__ raw,
                                              int* __restrict__ flag) {
    const int lane = threadIdx.x;
    int big = 0;
    #pragma unroll
    for (int i = 0; i < 16; i++) {
        const u32 w = raw[lane * 16 + i];
        float lo, hi; bf2x2(w, lo, hi);
        if (!(fabsf(lo) <= 16.0f)) big++;   // NaN also counts
        if (!(fabsf(hi) <= 16.0f)) big++;
    }
    #pragma unroll
    for (int o = 32; o >= 1; o >>= 1) big += __shfl_xor(big, o, 64);
    if (lane == 0) *flag = (big > 8) ? 1 : 0;
}

// ---------------- K1: transpose emb_W (H,V) -> embT (V,H) bf16 ------------------
__global__ __launch_bounds__(1024) void k_transpose(const void* __restrict__ embW,
                                                    u16* __restrict__ embT,
                                                    const int* __restrict__ flag) {
    const int dt = *flag;
    __shared__ u16 tile[32][33];
    const int v0 = blockIdx.x * 32;
    const int h0 = blockIdx.y * 32;
    const int tx = threadIdx.x, ty = threadIdx.y;
    const int v = v0 + tx, h = h0 + ty;
    if (v < V_) {
        u16 val;
        if (dt) val = f2bf(((const float*)embW)[(size_t)h * V_ + v]);
        else    val = ((const u16*)embW)[(size_t)h * V_ + v];
        tile[ty][tx] = val;
    }
    __syncthreads();
    const int vo = v0 + ty, ho = h0 + tx;
    if (vo < V_) embT[(size_t)vo * H_ + ho] = tile[tx][ty];
}

// ---------------- K2: gather seqs embeddings + LayerNorm1 -> x (M,H) bf16 -------
__global__ __launch_bounds__(256) void k_gather_ln1(const int* __restrict__ seqs,
                                                    const u16* __restrict__ embT,
                                                    const void* __restrict__ g1,
                                                    const void* __restrict__ b1,
                                                    u16* __restrict__ x,
                                                    const int* __restrict__ flag) {
    const int dt = *flag;
    const int wid = threadIdx.x >> 6, lane = threadIdx.x & 63;
    const int row = blockIdx.x * 4 + wid;          // m = b*T + t
    const int b = row / T_, t = row - b * T_;
    const int tok = seqs[b * L_ + t];
    const u32 p = ((const u32*)(embT + (size_t)tok * H_))[lane];
    float e0, e1; bf2x2(p, e0, e1);
    float s1 = e0 + e1, s2 = e0 * e0 + e1 * e1;
    #pragma unroll
    for (int o = 32; o >= 1; o >>= 1) {
        s1 += __shfl_xor(s1, o, 64);
        s2 += __shfl_xor(s2, o, 64);
    }
    const float mu  = s1 * (1.0f / H_);
    const float var = s2 * (1.0f / H_) - mu * mu;
    const float rs  = rsqrtf(var + 1e-8f);
    float ga, gb, ba, bb;
    if (dt) {
        const float2 gg = ((const float2*)g1)[lane];
        const float2 bb2 = ((const float2*)b1)[lane];
        ga = gg.x; gb = gg.y; ba = bb2.x; bb = bb2.y;
    } else {
        bf2x2(((const u32*)g1)[lane], ga, gb);
        bf2x2(((const u32*)b1)[lane], ba, bb);
    }
    const float x0 = (e0 - mu) * rs * ga + ba;
    const float x1 = (e1 - mu) * rs * gb + bb;
    ((u32*)(x + (size_t)row * H_))[lane] = packbf(x0, x1);
}

// ---------------- K3: gi = x @ Wih^T + bih  (M x 384, K=128) --------------------
// One block per 64-row strip of x; thread n owns Wih row n (packed bf16, 64 u32).
template <bool GIF32>
__global__ __launch_bounds__(384) void k_gi(const u16* __restrict__ x,
                                            const void* __restrict__ Wih,
                                            const void* __restrict__ bih,
                                            void* __restrict__ gi_,
                                            const int* __restrict__ flag) {
    const int dt = *flag;
    __shared__ float xs[64][H_];   // 32 KB
    const int n = threadIdx.x;
    const int m0 = blockIdx.x * 64;
    // stage x strip (bf16 -> fp32 in LDS), 1024 uint4 loads
    const uint4* xg = (const uint4*)(x + (size_t)m0 * H_);
    for (int idx = n; idx < 1024; idx += 384) {
        const uint4 q = xg[idx];
        const int e = idx * 8;
        const int mrow = e >> 7, kcol = e & 127;
        float f0,f1,f2,f3,f4,f5,f6,f7;
        bf2x2(q.x,f0,f1); bf2x2(q.y,f2,f3); bf2x2(q.z,f4,f5); bf2x2(q.w,f6,f7);
        float* d = &xs[mrow][kcol];
        d[0]=f0; d[1]=f1; d[2]=f2; d[3]=f3; d[4]=f4; d[5]=f5; d[6]=f6; d[7]=f7;
    }
    // Wih row n -> 64 packed u32 (128 bf16)
    u32 wreg[64];
    if (dt) {
        const float4* wg = (const float4*)((const float*)Wih + (size_t)n * H_);
        #pragma unroll
        for (int i = 0; i < 32; i++) {
            const float4 q = wg[i];
            wreg[i*2]   = packbf(q.x, q.y);
            wreg[i*2+1] = packbf(q.z, q.w);
        }
    } else {
        const uint4* wg = (const uint4*)((const u16*)Wih + (size_t)n * H_);
        #pragma unroll
        for (int i = 0; i < 16; i++) {
            const uint4 q = wg[i];
            wreg[i*4+0]=q.x; wreg[i*4+1]=q.y; wreg[i*4+2]=q.z; wreg[i*4+3]=q.w;
        }
    }
    const float bias = dt ? ((const float*)bih)[n] : bf2f(((const u16*)bih)[n]);
    __syncthreads();
    for (int mc = 0; mc < 64; mc += 16) {
        float acc[16];
        #pragma unroll
        for (int mm = 0; mm < 16; mm++) acc[mm] = bias;
        #pragma unroll
        for (int kk = 0; kk < H_; kk += 4) {
            float w0,w1,w2,w3;
            bf2x2(wreg[kk>>1],     w0, w1);
            bf2x2(wreg[(kk>>1)+1], w2, w3);
            #pragma unroll
            for (int mm = 0; mm < 16; mm++) {
                const float4 xv = *(const float4*)&xs[mc + mm][kk];
                acc[mm] = fmaf(w0, xv.x, fmaf(w1, xv.y,
                          fmaf(w2, xv.z, fmaf(w3, xv.w, acc[mm]))));
            }
        }
        if (GIF32) {
            float* go = (float*)gi_;
            #pragma unroll
            for (int mm = 0; mm < 16; mm++)
                go[(size_t)(m0 + mc + mm) * G3_ + n] = acc[mm];
        } else {
            u16* go = (u16*)gi_;
            #pragma unroll
            for (int mm = 0; mm < 16; mm++)
                go[(size_t)(m0 + mc + mm) * G3_ + n] = f2bf(acc[mm]);
        }
    }
}

// ---------------- K4: persistent GRU + LN2 + pos/neg dots -----------------------
// grid = 512 (one block per batch), block = 384 (thread n owns Whh row n).
template <bool GIF32>
__global__ __launch_bounds__(384) void k_gru(const int* __restrict__ seqs,
                                             const int* __restrict__ negs,
                                             const u16* __restrict__ embT,
                                             const void* __restrict__ Whh,
                                             const void* __restrict__ bhh,
                                             const void* __restrict__ g2,
                                             const void* __restrict__ b2,
                                             const void* __restrict__ gi_,
                                             void* __restrict__ out,
                                             const int* __restrict__ flag) {
    const int dt = *flag;
    __shared__ float h[2][H_];
    __shared__ float ghs[G3_];
    __shared__ float red[4];
    __shared__ float dred[4];
    const int n = threadIdx.x;
    const int b = blockIdx.x;
    const int lane = n & 63, wid = n >> 6;
    u32 wreg[64];
    if (dt) {
        const float4* wg = (const float4*)((const float*)Whh + (size_t)n * H_);
        #pragma unroll
        for (int i = 0; i < 32; i++) {
            const float4 q = wg[i];
            wreg[i*2]   = packbf(q.x, q.y);
            wreg[i*2+1] = packbf(q.z, q.w);
        }
    } else {
        const uint4* wg = (const uint4*)((const u16*)Whh + (size_t)n * H_);
        #pragma unroll
        for (int i = 0; i < 16; i++) {
            const uint4 q = wg[i];
            wreg[i*4+0]=q.x; wreg[i*4+1]=q.y; wreg[i*4+2]=q.z; wreg[i*4+3]=q.w;
        }
    }
    const float bias = dt ? ((const float*)bhh)[n] : bf2f(((const u16*)bhh)[n]);
    float g2v = 0.f, b2v = 0.f;
    if (n < H_) {
        if (dt) { g2v = ((const float*)g2)[n]; b2v = ((const float*)b2)[n]; }
        else    { g2v = bf2f(((const u16*)g2)[n]); b2v = bf2f(((const u16*)b2)[n]); }
        h[0][n] = 0.f;
    }
    const float* gif = (const float*)gi_;
    const u16*  gih = (const u16*)gi_;
    __syncthreads();
    for (int t = 0; t < T_; t++) {
        const int cur = t & 1, nxt = cur ^ 1;
        // ---- gh_n = bhh_n + Whh[n,:] . h  (all 384 threads) ----
        float acc = bias;
        #pragma unroll
        for (int kk = 0; kk < H_; kk += 4) {
            float w0,w1,w2,w3;
            bf2x2(wreg[kk>>1],     w0, w1);
            bf2x2(wreg[(kk>>1)+1], w2, w3);
            const float4 hv = *(const float4*)&h[cur][kk];
            acc = fmaf(w0, hv.x, fmaf(w1, hv.y,
                  fmaf(w2, hv.z, fmaf(w3, hv.w, acc))));
        }
        ghs[n] = acc;
        __syncthreads();
        // ---- gates + h update + LN stats (threads 0..127) ----
        float hn = 0.f;
        if (n < H_) {
            const size_t base = (size_t)(b * T_ + t) * G3_;
            float gir, giz, gin;
            if (GIF32) {
                gir = gif[base + n];
                giz = gif[base + H_ + n];
                gin = gif[base + 2*H_ + n];
            } else {
                gir = bf2f(gih[base + n]);
                giz = bf2f(gih[base + H_ + n]);
                gin = bf2f(gih[base + 2*H_ + n]);
            }
            const float r  = sigmoidf_(gir + ghs[n]);
            const float z  = sigmoidf_(giz + ghs[H_ + n]);
            const float nn = tanhf_(gin + r * ghs[2*H_ + n]);
            hn = (1.f - z) * nn + z * h[cur][n];
            h[nxt][n] = hn;
            float s1 = hn, s2 = hn * hn;
            #pragma unroll
            for (int o = 32; o >= 1; o >>= 1) {
                s1 += __shfl_xor(s1, o, 64);
                s2 += __shfl_xor(s2, o, 64);
            }
            if (lane == 0) { red[wid] = s1; red[2 + wid] = s2; }
        }
        __syncthreads();
        // ---- LN2 + pos/neg dot (threads 0..127) ----
        if (n < H_) {
            const float mu  = (red[0] + red[1]) * (1.0f / H_);
            const float var = (red[2] + red[3]) * (1.0f / H_) - mu * mu;
            const float rs  = rsqrtf(var + 1e-8f);
            const float lo  = (hn - mu) * rs * g2v + b2v;
            const int ptok = seqs[b * L_ + t + 1];
            const int ntok = negs[b * L_ + t + 1];
            float pe = lo * bf2f(embT[(size_t)ptok * H_ + n]);
            float ne = lo * bf2f(embT[(size_t)ntok * H_ + n]);
            #pragma unroll
            for (int o = 32; o >= 1; o >>= 1) {
                pe += __shfl_xor(pe, o, 64);
                ne += __shfl_xor(ne, o, 64);
            }
            if (lane == 0) { dred[wid] = pe; dred[2 + wid] = ne; }
        }
        __syncthreads();
        if (n == 0) {
            const float pv = dred[0] + dred[1];
            const float nv = dred[2] + dred[3];
            if (dt) {
                ((float*)out)[b * T_ + t]           = pv;
                ((float*)out)[B_ * T_ + b * T_ + t] = nv;
            } else {
                ((u16*)out)[b * T_ + t]           = f2bf(pv);
                ((u16*)out)[B_ * T_ + b * T_ + t] = f2bf(nv);
            }
        }
    }
}

extern "C" void kernel_launch(void* const* d_in, const int* in_sizes, int n_in,
                              void* d_out, int out_size, void* d_ws, size_t ws_size,
                              hipStream_t stream) {
    const int* seqs = (const int*)d_in[0];
    const int* negs = (const int*)d_in[1];
    const void* embW = d_in[2];
    const void* Wih  = d_in[3];
    const void* Whh  = d_in[4];
    const void* bih  = d_in[5];
    const void* bhh  = d_in[6];
    const void* g1   = d_in[7];
    const void* b1   = d_in[8];
    const void* g2   = d_in[9];
    const void* b2   = d_in[10];

    char* ws = (char*)d_ws;
    int* flag = (int*)ws;
    u16* embT = (u16*)(ws + OFF_EMBT);
    u16* x    = (u16*)(ws + OFF_X);
    void* gi  = (void*)(ws + OFF_GI);
    const size_t need_f32 = OFF_GI + (size_t)M_ * G3_ * 4ull;
    const bool gif32 = (ws_size >= need_f32);

    k_sniff<<<1, 64, 0, stream>>>((const u32*)embW, flag);
    k_transpose<<<dim3((V_ + 31) / 32, H_ / 32), dim3(32, 32), 0, stream>>>(embW, embT, flag);
    k_gather_ln1<<<M_ / 4, 256, 0, stream>>>(seqs, embT, g1, b1, x, flag);
    if (gif32) {
        k_gi<true><<<M_ / 64, G3_, 0, stream>>>(x, Wih, bih, gi, flag);
        k_gru<true><<<B_, G3_, 0, stream>>>(seqs, negs, embT, Whh, bhh, g2, b2, gi, d_out, flag);
    } else {
        k_gi<false><<<M_ / 64, G3_, 0, stream>>>(x, Wih, bih, gi, flag);
        k_gru<false><<<B_, G3_, 0, stream>>>(seqs, negs, embT, Whh, bhh, g2, b2, gi, d_out, flag);
    }
}

// Round 3
// 1435.770 us; speedup vs baseline: 1.0224x; 1.0224x over previous
//
#include <hip/hip_runtime.h>

typedef unsigned int u32;
typedef unsigned short u16;

#define B_   512
#define L_   201
#define T_   200
#define H_   128
#define V_   100001
#define G3_  384
#define M_   (B_*T_)   // 102400

// ws layout (bytes):
//   [0,16)       : dtype flag (int) from k_sniff: 1=fp32 inputs, 0=bf16 inputs
//   [256, +25600256) : embT (V,H) bf16
//   [25600768, ...)  : gi (M,384) fp32 (157286400 B) if ws fits, else bf16 (78643200 B)
#define OFF_EMBT  256
#define OFF_GI    25600768ull

__device__ __forceinline__ float bf2f(u16 a) {
    return __uint_as_float(((u32)a) << 16);
}
__device__ __forceinline__ void bf2x2(u32 p, float& lo, float& hi) {
    lo = __uint_as_float(p << 16);
    hi = __uint_as_float(p & 0xffff0000u);
}
__device__ __forceinline__ u16 f2bf(float f) {
    u32 u = __float_as_uint(f);
    u32 lsb = (u >> 16) & 1u;
    u += 0x7fffu + lsb;   // RNE
    return (u16)(u >> 16);
}
__device__ __forceinline__ u32 packbf(float a, float b) {
    return (u32)f2bf(a) | ((u32)f2bf(b) << 16);
}
__device__ __forceinline__ float sigmoidf_(float x) {
    return 1.0f / (1.0f + __expf(-x));
}
__device__ __forceinline__ float tanhf_(float x) {
    float e = __expf(2.0f * x);
    return 1.0f - 2.0f / (e + 1.0f);
}

// ---------------- K0: dtype sniffer --------------------------------------------
__global__ __launch_bounds__(64) void k_sniff(const u32* __restrict__ raw,
                                              int* __restrict__ flag) {
    const int lane = threadIdx.x;
    int big = 0;
    #pragma unroll
    for (int i = 0; i < 16; i++) {
        const u32 w = raw[lane * 16 + i];
        float lo, hi; bf2x2(w, lo, hi);
        if (!(fabsf(lo) <= 16.0f)) big++;   // NaN also counts
        if (!(fabsf(hi) <= 16.0f)) big++;
    }
    #pragma unroll
    for (int o = 32; o >= 1; o >>= 1) big += __shfl_xor(big, o, 64);
    if (lane == 0) *flag = (big > 8) ? 1 : 0;
}

// ---------------- K1: transpose emb_W (H,V) -> embT (V,H) bf16 ------------------
__global__ __launch_bounds__(1024) void k_transpose(const void* __restrict__ embW,
                                                    u16* __restrict__ embT,
                                                    const int* __restrict__ flag) {
    const int dt = *flag;
    __shared__ u16 tile[32][33];
    const int v0 = blockIdx.x * 32;
    const int h0 = blockIdx.y * 32;
    const int tx = threadIdx.x, ty = threadIdx.y;
    const int v = v0 + tx, h = h0 + ty;
    if (v < V_) {
        u16 val;
        if (dt) val = f2bf(((const float*)embW)[(size_t)h * V_ + v]);
        else    val = ((const u16*)embW)[(size_t)h * V_ + v];
        tile[ty][tx] = val;
    }
    __syncthreads();
    const int vo = v0 + ty, ho = h0 + tx;
    if (vo < V_) embT[(size_t)vo * H_ + ho] = tile[tx][ty];
}

// ---------------- K3: fused gather + LN1 + (gi = x @ Wih^T + bih) ---------------
// One block per 64-row strip; thread n owns Wih row n (128 bf16 packed in 64 u32).
#define XS_PAD 132
template <bool GIF32>
__global__ __launch_bounds__(384) void k_gi(const int* __restrict__ seqs,
                                            const u16* __restrict__ embT,
                                            const void* __restrict__ g1,
                                            const void* __restrict__ b1,
                                            const void* __restrict__ Wih,
                                            const void* __restrict__ bih,
                                            void* __restrict__ gi_,
                                            const int* __restrict__ flag) {
    const int dt = *flag;
    __shared__ float xs[64][XS_PAD];   // ~33.8 KB
    __shared__ float gbv[256];         // g1 | b1 as fp32
    const int n = threadIdx.x;
    const int m0 = blockIdx.x * 64;
    if (n < 128)      gbv[n] = dt ? ((const float*)g1)[n]       : bf2f(((const u16*)g1)[n]);
    else if (n < 256) gbv[n] = dt ? ((const float*)b1)[n - 128] : bf2f(((const u16*)b1)[n - 128]);
    // stage: gather embeddings for 64 rows into LDS as fp32
    for (int idx = n; idx < 1024; idx += 384) {
        const int row = idx >> 4, part = idx & 15;
        const int m = m0 + row;
        const int b = m / T_, t = m - b * T_;
        const int tok = seqs[b * L_ + t];
        const uint4 q = ((const uint4*)(embT + (size_t)tok * H_))[part];
        float f0,f1,f2,f3,f4,f5,f6,f7;
        bf2x2(q.x,f0,f1); bf2x2(q.y,f2,f3); bf2x2(q.z,f4,f5); bf2x2(q.w,f6,f7);
        float* d = &xs[row][part * 8];
        ((float4*)d)[0] = make_float4(f0,f1,f2,f3);
        ((float4*)d)[1] = make_float4(f4,f5,f6,f7);
    }
    // Wih row n -> regs
    u32 wreg[64];
    if (dt) {
        const float4* wg = (const float4*)((const float*)Wih + (size_t)n * H_);
        #pragma unroll
        for (int i = 0; i < 32; i++) {
            const float4 q = wg[i];
            wreg[i*2]   = packbf(q.x, q.y);
            wreg[i*2+1] = packbf(q.z, q.w);
        }
    } else {
        const uint4* wg = (const uint4*)((const u16*)Wih + (size_t)n * H_);
        #pragma unroll
        for (int i = 0; i < 16; i++) {
            const uint4 q = wg[i];
            wreg[i*4+0]=q.x; wreg[i*4+1]=q.y; wreg[i*4+2]=q.z; wreg[i*4+3]=q.w;
        }
    }
    const float bias = dt ? ((const float*)bih)[n] : bf2f(((const u16*)bih)[n]);
    __syncthreads();
    // LN1 in place: 4 threads per row
    if (n < 256) {
        const int row = n >> 2, q4 = n & 3;
        float* xr = &xs[row][q4 * 32];
        float s1 = 0.f, s2 = 0.f;
        #pragma unroll
        for (int j = 0; j < 32; j += 4) {
            const float4 v = *(const float4*)&xr[j];
            s1 += (v.x + v.y) + (v.z + v.w);
            s2 += (v.x*v.x + v.y*v.y) + (v.z*v.z + v.w*v.w);
        }
        s1 += __shfl_xor(s1, 1, 64); s2 += __shfl_xor(s2, 1, 64);
        s1 += __shfl_xor(s1, 2, 64); s2 += __shfl_xor(s2, 2, 64);
        const float mu  = s1 * (1.0f / H_);
        const float var = s2 * (1.0f / H_) - mu * mu;
        const float rs  = rsqrtf(var + 1e-8f);
        const float* gg = &gbv[q4 * 32];
        const float* bb = &gbv[128 + q4 * 32];
        #pragma unroll
        for (int j = 0; j < 32; j += 4) {
            float4 v = *(float4*)&xr[j];
            v.x = (v.x - mu) * rs * gg[j]   + bb[j];
            v.y = (v.y - mu) * rs * gg[j+1] + bb[j+1];
            v.z = (v.z - mu) * rs * gg[j+2] + bb[j+2];
            v.w = (v.w - mu) * rs * gg[j+3] + bb[j+3];
            *(float4*)&xr[j] = v;
        }
    }
    __syncthreads();
    // GEMM
    for (int mc = 0; mc < 64; mc += 16) {
        float acc[16];
        #pragma unroll
        for (int mm = 0; mm < 16; mm++) acc[mm] = bias;
        #pragma unroll
        for (int kk = 0; kk < H_; kk += 4) {
            float w0,w1,w2,w3;
            bf2x2(wreg[kk>>1],     w0, w1);
            bf2x2(wreg[(kk>>1)+1], w2, w3);
            #pragma unroll
            for (int mm = 0; mm < 16; mm++) {
                const float4 xv = *(const float4*)&xs[mc + mm][kk];
                acc[mm] = fmaf(w0, xv.x, fmaf(w1, xv.y,
                          fmaf(w2, xv.z, fmaf(w3, xv.w, acc[mm]))));
            }
        }
        if (GIF32) {
            float* go = (float*)gi_;
            #pragma unroll
            for (int mm = 0; mm < 16; mm++)
                go[(size_t)(m0 + mc + mm) * G3_ + n] = acc[mm];
        } else {
            u16* go = (u16*)gi_;
            #pragma unroll
            for (int mm = 0; mm < 16; mm++)
                go[(size_t)(m0 + mc + mm) * G3_ + n] = f2bf(acc[mm]);
        }
    }
}

// ---------------- K4: persistent GRU + LN2 + pos/neg dots -----------------------
// grid=512 (block per batch), block=384. Software-pipelined gi/emb prefetch,
// 2 barriers/step, 4-way-parallel dot accumulators, deferred out flush.
template <bool GIF32>
__global__ __launch_bounds__(384) void k_gru(const int* __restrict__ seqs,
                                             const int* __restrict__ negs,
                                             const u16* __restrict__ embT,
                                             const void* __restrict__ Whh,
                                             const void* __restrict__ bhh,
                                             const void* __restrict__ g2,
                                             const void* __restrict__ b2,
                                             const void* __restrict__ gi_,
                                             void* __restrict__ out,
                                             const int* __restrict__ flag) {
    const int dt = *flag;
    __shared__ float h[2][H_];
    __shared__ float ghs[G3_];
    __shared__ float gis[2][G3_];
    __shared__ float red[4];
    __shared__ float pbuf[T_][2];
    __shared__ float nbuf[T_][2];
    const int n = threadIdx.x;
    const int b = blockIdx.x;
    const int lane = n & 63, wid = n >> 6;
    u32 wreg[64];
    if (dt) {
        const float4* wg = (const float4*)((const float*)Whh + (size_t)n * H_);
        #pragma unroll
        for (int i = 0; i < 32; i++) {
            const float4 q = wg[i];
            wreg[i*2]   = packbf(q.x, q.y);
            wreg[i*2+1] = packbf(q.z, q.w);
        }
    } else {
        const uint4* wg = (const uint4*)((const u16*)Whh + (size_t)n * H_);
        #pragma unroll
        for (int i = 0; i < 16; i++) {
            const uint4 q = wg[i];
            wreg[i*4+0]=q.x; wreg[i*4+1]=q.y; wreg[i*4+2]=q.z; wreg[i*4+3]=q.w;
        }
    }
    const float bias = dt ? ((const float*)bhh)[n] : bf2f(((const u16*)bhh)[n]);
    float g2v = 0.f, b2v = 0.f;
    if (n < H_) {
        if (dt) { g2v = ((const float*)g2)[n]; b2v = ((const float*)b2)[n]; }
        else    { g2v = bf2f(((const u16*)g2)[n]); b2v = bf2f(((const u16*)b2)[n]); }
        h[0][n] = 0.f;
    }
    const float* gif = (const float*)gi_;
    const u16*  gih = (const u16*)gi_;
    const int sbase = b * L_;
    // prologue prefetch: gi(0) direct to LDS, gi(1)/emb(0)/emb(1) to regs
    {
        const size_t o0 = (size_t)(b * T_ + 0) * G3_ + n;
        gis[0][n] = GIF32 ? gif[o0] : bf2f(gih[o0]);
    }
    float gnext;
    {
        const size_t o1 = (size_t)(b * T_ + 1) * G3_ + n;
        gnext = GIF32 ? gif[o1] : bf2f(gih[o1]);
    }
    float pe_c = 0.f, ne_c = 0.f, pe_n = 0.f, ne_n = 0.f;
    if (n < H_) {
        pe_c = bf2f(embT[(size_t)seqs[sbase + 1] * H_ + n]);
        ne_c = bf2f(embT[(size_t)negs[sbase + 1] * H_ + n]);
        pe_n = bf2f(embT[(size_t)seqs[sbase + 2] * H_ + n]);
        ne_n = bf2f(embT[(size_t)negs[sbase + 2] * H_ + n]);
    }
    __syncthreads();
    for (int t = 0; t < T_; t++) {
        const int cur = t & 1;
        // issue prefetches for step t+2 (recurrence-independent)
        float gi2 = 0.f, pe2 = 0.f, ne2 = 0.f;
        if (t + 2 < T_) {
            const size_t o2 = (size_t)(b * T_ + t + 2) * G3_ + n;
            gi2 = GIF32 ? gif[o2] : bf2f(gih[o2]);
            if (n < H_) {
                pe2 = bf2f(embT[(size_t)seqs[sbase + t + 3] * H_ + n]);
                ne2 = bf2f(embT[(size_t)negs[sbase + t + 3] * H_ + n]);
            }
        }
        // gh_n = bhh_n + Whh[n,:] . h  — 4 parallel accumulator chains
        float a0 = 0.f, a1 = 0.f, a2 = 0.f, a3 = bias;
        #pragma unroll
        for (int kk = 0; kk < H_; kk += 8) {
            const int r = kk >> 1;
            float w0,w1,w2,w3,w4,w5,w6,w7;
            bf2x2(wreg[r],   w0, w1);
            bf2x2(wreg[r+1], w2, w3);
            bf2x2(wreg[r+2], w4, w5);
            bf2x2(wreg[r+3], w6, w7);
            const float4 h0 = *(const float4*)&h[cur][kk];
            const float4 h1 = *(const float4*)&h[cur][kk + 4];
            a0 = fmaf(w0, h0.x, a0); a1 = fmaf(w1, h0.y, a1);
            a2 = fmaf(w2, h0.z, a2); a3 = fmaf(w3, h0.w, a3);
            a0 = fmaf(w4, h1.x, a0); a1 = fmaf(w5, h1.y, a1);
            a2 = fmaf(w6, h1.z, a2); a3 = fmaf(w7, h1.w, a3);
        }
        ghs[n] = (a0 + a1) + (a2 + a3);
        __syncthreads();                      // barrier 1
        gis[cur ^ 1][n] = gnext;              // stash prefetched gi(t+1)
        float hn = 0.f;
        if (n < H_) {
            const float gir = gis[cur][n];
            const float giz = gis[cur][H_ + n];
            const float gin = gis[cur][2 * H_ + n];
            const float r  = sigmoidf_(gir + ghs[n]);
            const float z  = sigmoidf_(giz + ghs[H_ + n]);
            const float nn = tanhf_(gin + r * ghs[2 * H_ + n]);
            hn = (1.f - z) * nn + z * h[cur][n];
            h[cur ^ 1][n] = hn;
            float s1 = hn, s2 = hn * hn;
            #pragma unroll
            for (int o = 32; o >= 1; o >>= 1) {
                s1 += __shfl_xor(s1, o, 64);
                s2 += __shfl_xor(s2, o, 64);
            }
            if (lane == 0) { red[wid] = s1; red[2 + wid] = s2; }
        }
        __syncthreads();                      // barrier 2
        if (n < H_) {
            const float mu  = (red[0] + red[1]) * (1.0f / H_);
            const float var = (red[2] + red[3]) * (1.0f / H_) - mu * mu;
            const float rs  = rsqrtf(var + 1e-8f);
            const float lo  = (hn - mu) * rs * g2v + b2v;
            float pe = lo * pe_c;
            float ne = lo * ne_c;
            #pragma unroll
            for (int o = 32; o >= 1; o >>= 1) {
                pe += __shfl_xor(pe, o, 64);
                ne += __shfl_xor(ne, o, 64);
            }
            if (lane == 0) { pbuf[t][wid] = pe; nbuf[t][wid] = ne; }
        }
        // rotate pipeline registers
        gnext = gi2; pe_c = pe_n; ne_c = ne_n; pe_n = pe2; ne_n = ne2;
    }
    __syncthreads();
    for (int t = n; t < T_; t += 384) {
        const float pv = pbuf[t][0] + pbuf[t][1];
        const float nv = nbuf[t][0] + nbuf[t][1];
        if (dt) {
            ((float*)out)[b * T_ + t]           = pv;
            ((float*)out)[B_ * T_ + b * T_ + t] = nv;
        } else {
            ((u16*)out)[b * T_ + t]           = f2bf(pv);
            ((u16*)out)[B_ * T_ + b * T_ + t] = f2bf(nv);
        }
    }
}

extern "C" void kernel_launch(void* const* d_in, const int* in_sizes, int n_in,
                              void* d_out, int out_size, void* d_ws, size_t ws_size,
                              hipStream_t stream) {
    const int* seqs = (const int*)d_in[0];
    const int* negs = (const int*)d_in[1];
    const void* embW = d_in[2];
    const void* Wih  = d_in[3];
    const void* Whh  = d_in[4];
    const void* bih  = d_in[5];
    const void* bhh  = d_in[6];
    const void* g1   = d_in[7];
    const void* b1   = d_in[8];
    const void* g2   = d_in[9];
    const void* b2   = d_in[10];

    char* ws = (char*)d_ws;
    int* flag = (int*)ws;
    u16* embT = (u16*)(ws + OFF_EMBT);
    void* gi  = (void*)(ws + OFF_GI);
    const size_t need_f32 = OFF_GI + (size_t)M_ * G3_ * 4ull;
    const bool gif32 = (ws_size >= need_f32);

    k_sniff<<<1, 64, 0, stream>>>((const u32*)embW, flag);
    k_transpose<<<dim3((V_ + 31) / 32, H_ / 32), dim3(32, 32), 0, stream>>>(embW, embT, flag);
    if (gif32) {
        k_gi<true><<<M_ / 64, G3_, 0, stream>>>(seqs, embT, g1, b1, Wih, bih, gi, flag);
        k_gru<true><<<B_, G3_, 0, stream>>>(seqs, negs, embT, Whh, bhh, g2, b2, gi, d_out, flag);
    } else {
        k_gi<false><<<M_ / 64, G3_, 0, stream>>>(seqs, embT, g1, b1, Wih, bih, gi, flag);
        k_gru<false><<<B_, G3_, 0, stream>>>(seqs, negs, embT, Whh, bhh, g2, b2, gi, d_out, flag);
    }
}

// Round 5
// 611.907 us; speedup vs baseline: 2.3990x; 2.3464x over previous
//
#include <hip/hip_runtime.h>

typedef unsigned int u32;
typedef unsigned short u16;
typedef __attribute__((ext_vector_type(8))) short bf16x8;
typedef __attribute__((ext_vector_type(4))) float f32x4;

#define B_   512
#define L_   201
#define T_   200
#define H_   128
#define V_   100001
#define GPB  16              // batches per block
#define NBLK (B_/GPB)        // 32 blocks
// Row stride for hbuf/xbuf in u16. MUST be >= 128 (H_) — round 4 bug was HS=88
// which made 256B rows overlap at 176B stride. 136 = 128 + 8 pad; 272B stride
// keeps 16B alignment for b128 fragment reads and breaks pow2 banking.
#define HS   136

#define OFF_EMBT 256

__device__ __forceinline__ float bf2f(u16 a) {
    return __uint_as_float(((u32)a) << 16);
}
__device__ __forceinline__ void bf2x2(u32 p, float& lo, float& hi) {
    lo = __uint_as_float(p << 16);
    hi = __uint_as_float(p & 0xffff0000u);
}
__device__ __forceinline__ u16 f2bf(float f) {
    u32 u = __float_as_uint(f);
    u32 lsb = (u >> 16) & 1u;
    u += 0x7fffu + lsb;   // RNE
    return (u16)(u >> 16);
}
__device__ __forceinline__ u32 packbf(float a, float b) {
    return (u32)f2bf(a) | ((u32)f2bf(b) << 16);
}
__device__ __forceinline__ float sigmoidf_(float x) {
    return 1.0f / (1.0f + __expf(-x));
}
__device__ __forceinline__ float tanhf_(float x) {
    float e = __expf(2.0f * x);
    return 1.0f - 2.0f / (e + 1.0f);
}
// sum-reduce a,b over a 32-lane half-wave
__device__ __forceinline__ void halfred2(float& a, float& b) {
    #pragma unroll
    for (int o = 1; o <= 16; o <<= 1) {
        a += __shfl_xor(a, o, 64);
        b += __shfl_xor(b, o, 64);
    }
}
__device__ __forceinline__ float ldv(const void* p, int dt, int i) {
    return dt ? ((const float*)p)[i] : bf2f(((const u16*)p)[i]);
}
// load 8 consecutive weights (row-major, 128/row) as a bf16x8 MFMA fragment
__device__ __forceinline__ bf16x8 load_frag(const void* W, int dt, int row, int koff) {
    union { bf16x8 v; u32 uu[4]; uint4 q; } r;
    if (dt) {
        const float4* p = (const float4*)((const float*)W + (size_t)row * H_ + koff);
        const float4 a = p[0], b = p[1];
        r.uu[0] = packbf(a.x, a.y); r.uu[1] = packbf(a.z, a.w);
        r.uu[2] = packbf(b.x, b.y); r.uu[3] = packbf(b.z, b.w);
    } else {
        r.q = *(const uint4*)((const u16*)W + (size_t)row * H_ + koff);
    }
    return r.v;
}
#define MFMA16(a, b, c) __builtin_amdgcn_mfma_f32_16x16x32_bf16((a), (b), (c), 0, 0, 0)

// ---------------- K0: dtype sniffer --------------------------------------------
__global__ __launch_bounds__(64) void k_sniff(const u32* __restrict__ raw,
                                              int* __restrict__ flag) {
    const int lane = threadIdx.x;
    int big = 0;
    #pragma unroll
    for (int i = 0; i < 16; i++) {
        const u32 w = raw[lane * 16 + i];
        float lo, hi; bf2x2(w, lo, hi);
        if (!(fabsf(lo) <= 16.0f)) big++;   // NaN counts
        if (!(fabsf(hi) <= 16.0f)) big++;
    }
    #pragma unroll
    for (int o = 32; o >= 1; o >>= 1) big += __shfl_xor(big, o, 64);
    if (lane == 0) *flag = (big > 8) ? 1 : 0;
}

// ---------------- K1: transpose emb_W (H,V) -> embT (V,H) bf16 ------------------
__global__ __launch_bounds__(1024) void k_transpose(const void* __restrict__ embW,
                                                    u16* __restrict__ embT,
                                                    const int* __restrict__ flag) {
    const int dt = *flag;
    __shared__ u16 tile[32][33];
    const int v0 = blockIdx.x * 32;
    const int h0 = blockIdx.y * 32;
    const int tx = threadIdx.x, ty = threadIdx.y;
    const int v = v0 + tx, h = h0 + ty;
    if (v < V_) {
        u16 val;
        if (dt) val = f2bf(((const float*)embW)[(size_t)h * V_ + v]);
        else    val = ((const u16*)embW)[(size_t)h * V_ + v];
        tile[ty][tx] = val;
    }
    __syncthreads();
    const int vo = v0 + ty, ho = h0 + tx;
    if (vo < V_) embT[(size_t)vo * H_ + ho] = tile[tx][ty];
}

// ---------------- K2: fused persistent GRU (gather+LN1+gi+gh+gates+LN2+dots) ----
// grid = 32 blocks x 512 threads (8 waves). 16 batches/block.
// Wave w owns M-tiles {w, 8+w, 16+w} of Wih/Whh (r/z/n slices, same i-range)
// -> gates are lane-local in MFMA C-layout. One barrier per step.
__global__ __launch_bounds__(512, 2) void k_fused(
        const int* __restrict__ seqs, const int* __restrict__ negs,
        const u16* __restrict__ embT,
        const void* __restrict__ Wih, const void* __restrict__ Whh,
        const void* __restrict__ bih, const void* __restrict__ bhh,
        const void* __restrict__ g1, const void* __restrict__ b1,
        const void* __restrict__ g2, const void* __restrict__ b2,
        void* __restrict__ out, const int* __restrict__ flag)
{
    const int dt = *flag;
    __shared__ int tokS[GPB * L_];          // 12.9 KB
    __shared__ int tokN[GPB * L_];          // 12.9 KB
    __shared__ u16 hbuf[2][GPB * HS];       // 8.7 KB  h_t as bf16, [n][k]
    __shared__ u16 xbuf[4][GPB * HS];       // 17.4 KB LN1(x_t) ring

    const int tid  = threadIdx.x;
    const int w    = tid >> 6;        // wave 0..7
    const int L    = tid & 63;
    const int q    = L >> 4;          // quad 0..3
    const int u    = L & 15;          // MFMA col (batch) / A-row within tile
    const int lk   = L & 31;
    const int dotb = 2 * w + (L >> 5);    // batch handled for x-pipe/dot
    const int dotk = lk * 4;              // k-base (4 elems) for x-pipe/dot
    const int B0   = blockIdx.x * GPB;

    // ---- prologue: tokens -> LDS -------------------------------------------
    for (int i = tid; i < GPB * L_; i += 512) {
        const int n = i / L_;
        const int j = i - n * L_;
        tokS[i] = seqs[(B0 + n) * L_ + j];
        tokN[i] = negs[(B0 + n) * L_ + j];
    }
    for (int i = tid; i < GPB * HS; i += 512) hbuf[0][i] = 0;

    // ---- weights -> A-fragments (registers, loop-invariant) ----------------
    bf16x8 wa[12], xa[12];
    #pragma unroll
    for (int g = 0; g < 3; g++) {
        #pragma unroll
        for (int c = 0; c < 4; c++) {
            const int row  = g * H_ + w * 16 + u;
            const int koff = c * 32 + q * 8;
            wa[g * 4 + c] = load_frag(Whh, dt, row, koff);
            xa[g * 4 + c] = load_frag(Wih, dt, row, koff);
        }
    }
    // biases at this lane's C positions: i = w*16 + q*4 + r
    float sbr[4], sbz[4], bin_[4], bhn_[4];
    #pragma unroll
    for (int r = 0; r < 4; r++) {
        const int i = w * 16 + q * 4 + r;
        sbr[r]  = ldv(bih, dt, i)          + ldv(bhh, dt, i);
        sbz[r]  = ldv(bih, dt, H_ + i)     + ldv(bhh, dt, H_ + i);
        bin_[r] = ldv(bih, dt, 2 * H_ + i);
        bhn_[r] = ldv(bhh, dt, 2 * H_ + i);
    }
    float g1v[4], b1v[4], g2v[4], b2v[4];
    #pragma unroll
    for (int j = 0; j < 4; j++) {
        g1v[j] = ldv(g1, dt, dotk + j);
        b1v[j] = ldv(b1, dt, dotk + j);
        g2v[j] = ldv(g2, dt, dotk + j);
        b2v[j] = ldv(b2, dt, dotk + j);
    }
    float hst[4] = {0.f, 0.f, 0.f, 0.f};   // fp32 h-state at this lane's C slots
    __syncthreads();

    // ---- x-pipeline prologue: fill xbuf slots 0,1 --------------------------
    #pragma unroll
    for (int tp = 0; tp < 2; tp++) {
        const int tok = tokS[dotb * L_ + tp];
        const uint2 e = *(const uint2*)&embT[(size_t)tok * H_ + dotk];
        float f0, f1, f2, f3; bf2x2(e.x, f0, f1); bf2x2(e.y, f2, f3);
        float s1 = (f0 + f1) + (f2 + f3);
        float s2 = (f0*f0 + f1*f1) + (f2*f2 + f3*f3);
        halfred2(s1, s2);
        const float mu = s1 * (1.0f / H_);
        const float rs = rsqrtf(s2 * (1.0f / H_) - mu * mu + 1e-8f);
        uint2 xw;
        xw.x = packbf((f0-mu)*rs*g1v[0]+b1v[0], (f1-mu)*rs*g1v[1]+b1v[1]);
        xw.y = packbf((f2-mu)*rs*g1v[2]+b1v[2], (f3-mu)*rs*g1v[3]+b1v[3]);
        *(uint2*)&xbuf[tp][dotb * HS + dotk] = xw;
    }
    __syncthreads();

    uint2 pPu = {0, 0}, pNu = {0, 0};       // emb prefetch consumed at iter t (for s=t-1)

    for (int t = 0; t <= T_; t++) {
        const int cur = t & 1;
        // -- early independent loads (fill the MFMA shadow) --
        uint2 pPn = {0, 0}, pNn = {0, 0};
        if (t < T_) {
            const int pt = tokS[dotb * L_ + t + 1];
            const int nt = tokN[dotb * L_ + t + 1];
            pPn = *(const uint2*)&embT[(size_t)pt * H_ + dotk];
            pNn = *(const uint2*)&embT[(size_t)nt * H_ + dotk];
        }
        uint2 xg = {0, 0};
        if (t + 2 < T_) {
            const int xt = tokS[dotb * L_ + t + 2];
            xg = *(const uint2*)&embT[(size_t)xt * H_ + dotk];
        }
        // -- recurrence: B-frags -> 24 MFMA -> gates -> h' -> hbuf[nxt] --
        if (t < T_) {
            bf16x8 hbv[4], xbv[4];
            #pragma unroll
            for (int c = 0; c < 4; c++) {
                hbv[c] = *(const bf16x8*)&hbuf[cur][u * HS + c * 32 + q * 8];
                xbv[c] = *(const bf16x8*)&xbuf[t & 3][u * HS + c * 32 + q * 8];
            }
            f32x4 gr = {0,0,0,0}, gz = {0,0,0,0}, gn = {0,0,0,0};
            f32x4 ir = {0,0,0,0}, iz = {0,0,0,0}, inn = {0,0,0,0};
            #pragma unroll
            for (int c = 0; c < 4; c++) {
                gr  = MFMA16(wa[0*4+c], hbv[c], gr);
                gz  = MFMA16(wa[1*4+c], hbv[c], gz);
                gn  = MFMA16(wa[2*4+c], hbv[c], gn);
                ir  = MFMA16(xa[0*4+c], xbv[c], ir);
                iz  = MFMA16(xa[1*4+c], xbv[c], iz);
                inn = MFMA16(xa[2*4+c], xbv[c], inn);
            }
            float hp[4];
            #pragma unroll
            for (int r = 0; r < 4; r++) {
                const float rr = sigmoidf_(ir[r] + gr[r] + sbr[r]);
                const float zz = sigmoidf_(iz[r] + gz[r] + sbz[r]);
                const float nn = tanhf_((inn[r] + bin_[r]) + rr * (gn[r] + bhn_[r]));
                const float hn = (1.f - zz) * nn + zz * hst[r];
                hst[r] = hn; hp[r] = hn;
            }
            uint2 hw;
            hw.x = packbf(hp[0], hp[1]);
            hw.y = packbf(hp[2], hp[3]);
            *(uint2*)&hbuf[cur ^ 1][u * HS + w * 16 + q * 4] = hw;
        }
        // -- x-pipeline: LN1 for step t+2 into ring slot (t+2)&3 --
        if (t + 2 < T_) {
            float f0, f1, f2, f3; bf2x2(xg.x, f0, f1); bf2x2(xg.y, f2, f3);
            float s1 = (f0 + f1) + (f2 + f3);
            float s2 = (f0*f0 + f1*f1) + (f2*f2 + f3*f3);
            halfred2(s1, s2);
            const float mu = s1 * (1.0f / H_);
            const float rs = rsqrtf(s2 * (1.0f / H_) - mu * mu + 1e-8f);
            uint2 xw;
            xw.x = packbf((f0-mu)*rs*g1v[0]+b1v[0], (f1-mu)*rs*g1v[1]+b1v[1]);
            xw.y = packbf((f2-mu)*rs*g1v[2]+b1v[2], (f3-mu)*rs*g1v[3]+b1v[3]);
            *(uint2*)&xbuf[(t + 2) & 3][dotb * HS + dotk] = xw;
        }
        // -- LN2 + pos/neg dots for step s = t-1 (h_t is in hbuf[cur]) --
        if (t >= 1) {
            const int s = t - 1;
            const uint2 hh = *(const uint2*)&hbuf[cur][dotb * HS + dotk];
            float h0, h1, h2, h3; bf2x2(hh.x, h0, h1); bf2x2(hh.y, h2, h3);
            float s1 = (h0 + h1) + (h2 + h3);
            float s2 = (h0*h0 + h1*h1) + (h2*h2 + h3*h3);
            halfred2(s1, s2);
            const float mu = s1 * (1.0f / H_);
            const float rs = rsqrtf(s2 * (1.0f / H_) - mu * mu + 1e-8f);
            const float lo0 = (h0 - mu) * rs * g2v[0] + b2v[0];
            const float lo1 = (h1 - mu) * rs * g2v[1] + b2v[1];
            const float lo2 = (h2 - mu) * rs * g2v[2] + b2v[2];
            const float lo3 = (h3 - mu) * rs * g2v[3] + b2v[3];
            float p0, p1, p2, p3, n0, n1, n2, n3;
            bf2x2(pPu.x, p0, p1); bf2x2(pPu.y, p2, p3);
            bf2x2(pNu.x, n0, n1); bf2x2(pNu.y, n2, n3);
            float pe = (lo0*p0 + lo1*p1) + (lo2*p2 + lo3*p3);
            float ne = (lo0*n0 + lo1*n1) + (lo2*n2 + lo3*n3);
            halfred2(pe, ne);
            if (lk == 0) {
                if (dt) {
                    ((float*)out)[(B0 + dotb) * T_ + s]           = pe;
                    ((float*)out)[B_ * T_ + (B0 + dotb) * T_ + s] = ne;
                } else {
                    ((u16*)out)[(B0 + dotb) * T_ + s]             = f2bf(pe);
                    ((u16*)out)[B_ * T_ + (B0 + dotb) * T_ + s]   = f2bf(ne);
                }
            }
        }
        pPu = pPn; pNu = pNn;
        __syncthreads();
    }
}

extern "C" void kernel_launch(void* const* d_in, const int* in_sizes, int n_in,
                              void* d_out, int out_size, void* d_ws, size_t ws_size,
                              hipStream_t stream) {
    const int* seqs = (const int*)d_in[0];
    const int* negs = (const int*)d_in[1];
    const void* embW = d_in[2];
    const void* Wih  = d_in[3];
    const void* Whh  = d_in[4];
    const void* bih  = d_in[5];
    const void* bhh  = d_in[6];
    const void* g1   = d_in[7];
    const void* b1   = d_in[8];
    const void* g2   = d_in[9];
    const void* b2   = d_in[10];

    char* ws = (char*)d_ws;
    int* flag = (int*)ws;
    u16* embT = (u16*)(ws + OFF_EMBT);

    k_sniff<<<1, 64, 0, stream>>>((const u32*)embW, flag);
    k_transpose<<<dim3((V_ + 31) / 32, H_ / 32), dim3(32, 32), 0, stream>>>(embW, embT, flag);
    k_fused<<<NBLK, 512, 0, stream>>>(seqs, negs, embT, Wih, Whh, bih, bhh,
                                      g1, b1, g2, b2, d_out, flag);
}